// Round 7
// baseline (522.192 us; speedup 1.0000x reference)
//
#include <hip/hip_runtime.h>
#include <stdint.h>
#include <math.h>

#define NAG 8192
#define NB  144          // partial row stride: 128 feats + deg col(128) + pad to 9*16
#define BM  64           // M rows per block
#define LDA 72           // LDS row stride (shorts) for A tile (64 + 8 pad)
#define LDB 72           // LDS row stride for B tile
#define NSPLIT 8         // K splits (fp16 private partials, no atomics)

typedef __attribute__((ext_vector_type(8))) short short8;
typedef __attribute__((ext_vector_type(4))) float floatx4;

__device__ __forceinline__ float bf2f(unsigned short u) {
    union { uint32_t i; float f; } v; v.i = ((uint32_t)u) << 16; return v.f;
}
__device__ __forceinline__ unsigned short f2bf(float f) {
    union { float f; uint32_t i; } v; v.f = f;
    uint32_t x = v.i;
    return (unsigned short)((x + 0x7FFFu + ((x >> 16) & 1u)) >> 16);  // RNE
}
__device__ __forceinline__ unsigned short f2h(float f) {
    union { _Float16 h; unsigned short u; } v; v.h = (_Float16)f; return v.u;
}
__device__ __forceinline__ float h2f(unsigned short u) {
    union { _Float16 h; unsigned short u; } v; v.u = u; return (float)v.h;
}

// ---------------- Kernel 0: detect float storage dtype from W1 raw bits ----------------
__global__ __launch_bounds__(64) void k0_init(
    int* __restrict__ flag, const unsigned short* __restrict__ W1raw)
{
    int big = 0;
    #pragma unroll
    for (int j = 0; j < 8; ++j) {
        float v = bf2f(W1raw[threadIdx.x * 8 + j]);
        if (!(fabsf(v) <= 1e6f)) big = 1;   // catches huge and NaN (fp32 mantissa noise)
    }
    unsigned long long m = __ballot(big);
    if (threadIdx.x == 0) *flag = (m != 0ull) ? 1 : 0;
}

// ---------------- Kernel 1: h = tanh(obs@W1+b1); write h_f32 and hT_bf16 ----------------
__global__ __launch_bounds__(256) void k1_encode(
    const void* __restrict__ obs,   // [8192][64] fp32 or bf16
    const void* __restrict__ W1,    // [64][128]
    const void* __restrict__ b1,    // [128]
    const int* __restrict__ flag,
    float* __restrict__ h_f32,      // [8192][128]
    unsigned short* __restrict__ hT)// [144][8192] bf16 (row128=ones, 129..143=0)
{
    __shared__ float obs_lds[32][68];
    __shared__ unsigned short ht_lds[128][33];
    const int t = threadIdx.x;
    const int abase = blockIdx.x * 32;
    const bool isf = (*flag != 0);

    {   // stage obs tile 32x64
        int a = t >> 3, c0 = (t & 7) * 8;
        if (isf) {
            const float* p = (const float*)obs;
            #pragma unroll
            for (int j = 0; j < 8; ++j)
                obs_lds[a][c0 + j] = p[(size_t)(abase + a) * 64 + c0 + j];
        } else {
            const unsigned short* p = (const unsigned short*)obs;
            #pragma unroll
            for (int j = 0; j < 8; ++j)
                obs_lds[a][c0 + j] = bf2f(p[(size_t)(abase + a) * 64 + c0 + j]);
        }
    }
    __syncthreads();

    const int o = t & 127;
    const int half = t >> 7;          // wave-uniform
    float acc[16];
    if (isf) {
        const float* Wp = (const float*)W1;
        float bias = ((const float*)b1)[o];
        #pragma unroll
        for (int i = 0; i < 16; ++i) acc[i] = bias;
        for (int k0 = 0; k0 < 64; k0 += 8) {
            float w[8];
            #pragma unroll
            for (int j = 0; j < 8; ++j) w[j] = Wp[(k0 + j) * 128 + o];
            #pragma unroll
            for (int j = 0; j < 8; ++j)
                #pragma unroll
                for (int i = 0; i < 16; ++i)
                    acc[i] = fmaf(obs_lds[half * 16 + i][k0 + j], w[j], acc[i]);
        }
    } else {
        const unsigned short* Wp = (const unsigned short*)W1;
        float bias = bf2f(((const unsigned short*)b1)[o]);
        #pragma unroll
        for (int i = 0; i < 16; ++i) acc[i] = bias;
        for (int k0 = 0; k0 < 64; k0 += 8) {
            float w[8];
            #pragma unroll
            for (int j = 0; j < 8; ++j) w[j] = bf2f(Wp[(k0 + j) * 128 + o]);
            #pragma unroll
            for (int j = 0; j < 8; ++j)
                #pragma unroll
                for (int i = 0; i < 16; ++i)
                    acc[i] = fmaf(obs_lds[half * 16 + i][k0 + j], w[j], acc[i]);
        }
    }
    #pragma unroll
    for (int i = 0; i < 16; ++i) {
        float th = tanhf(acc[i]);
        int a = half * 16 + i;
        h_f32[(size_t)(abase + a) * 128 + o] = th;
        ht_lds[o][a] = f2bf(th);
    }
    __syncthreads();

    for (int p = 0; p < 18; ++p) {
        int n = p * 8 + (t >> 5);
        int a = t & 31;
        unsigned short v;
        if (n < 128)       v = ht_lds[n][a];
        else if (n == 128) v = 0x3F80;     // 1.0 bf16 -> deg column
        else               v = 0;
        hT[(size_t)n * NAG + abase + a] = v;
    }
}

// ---------------- Kernel 2: Cp16[ks] = adj[:, kslice] @ [h|1|0]  (bf16 MFMA) ----------------
// Round-2's PROVEN-CLEAN register shape: 256 thr, 4 waves, each wave = one 16-row strip
// x 9 uniform N-tiles (VGPR 44, WRITE 18 MB there). Added: depth-2 A + depth-1 B register
// prefetch (round-3 pattern), NSPLIT=8 -> 1024 blocks (4/CU), fp16 private partials.
__global__ __launch_bounds__(256, 4) void k2_msggemm(
    const int* __restrict__ adj,              // [8192][8192] int32 {0,1}
    const unsigned short* __restrict__ hT,    // [144][8192] bf16
    unsigned short* __restrict__ Cp16)        // [NSPLIT][8192][144] fp16 (fully overwritten)
{
    __shared__ __align__(16) unsigned short Alds[BM * LDA];   //  9216 B
    __shared__ __align__(16) unsigned short Blds[NB * LDB];   // 20736 B
    const int t = threadIdx.x;
    const int mtile = blockIdx.x & 127;       // 128 M-tiles of 64 rows
    const int ks = blockIdx.x >> 7;           // 8 K-splits of 1024
    const int row0 = mtile * BM;
    const int kbeg = ks * 1024;

    const int wave = t >> 6, lane = t & 63;
    const int fm = lane & 15, quad = lane >> 4;

    floatx4 acc[9];
    #pragma unroll
    for (int i = 0; i < 9; ++i) acc[i] = (floatx4)0.f;

    const int ar = t >> 2, aq = t & 3;    // A staging: 64 rows x 4 quarters of 16 ints
    const int bln = t & 7, brow = t >> 3; // B staging: 8-short chunk, row-offset

    const int* aP = adj + (size_t)(row0 + ar) * NAG + aq * 16;
    int4 rA0[4], rA1[4];
    uint4 rB[5];

#define LOADA(R, K) do { \
        _Pragma("unroll") \
        for (int c = 0; c < 4; ++c) \
            (R)[c] = *reinterpret_cast<const int4*>(aP + (K) + c * 4); \
    } while (0)
#define LOADB(K) do { \
        _Pragma("unroll") \
        for (int p = 0; p < 5; ++p) { \
            int n = p * 32 + brow; \
            if (n < NB) rB[p] = *reinterpret_cast<const uint4*>(hT + (size_t)n * NAG + (K) + bln * 8); \
        } \
    } while (0)
#define STOREA(R) do { \
        _Pragma("unroll") \
        for (int c = 0; c < 4; ++c) { \
            uint32_t d0 = ((uint32_t)(R)[c].x | ((uint32_t)(R)[c].y << 16)) * 0x3F80u; \
            uint32_t d1 = ((uint32_t)(R)[c].z | ((uint32_t)(R)[c].w << 16)) * 0x3F80u; \
            *reinterpret_cast<uint2*>(&Alds[ar * LDA + aq * 16 + c * 4]) = make_uint2(d0, d1); \
        } \
    } while (0)
#define STOREB() do { \
        _Pragma("unroll") \
        for (int p = 0; p < 5; ++p) { \
            int n = p * 32 + brow; \
            if (n < NB) *reinterpret_cast<uint4*>(&Blds[n * LDB + bln * 8]) = rB[p]; \
        } \
    } while (0)
#define COMPUTE() do { \
        _Pragma("unroll") \
        for (int kk = 0; kk < 64; kk += 32) { \
            short8 af = *reinterpret_cast<const short8*>(&Alds[(wave * 16 + fm) * LDA + kk + quad * 8]); \
            _Pragma("unroll") \
            for (int j = 0; j < 9; ++j) { \
                short8 bf = *reinterpret_cast<const short8*>(&Blds[(j * 16 + fm) * LDB + kk + quad * 8]); \
                acc[j] = __builtin_amdgcn_mfma_f32_16x16x32_bf16(af, bf, acc[j], 0, 0, 0); \
            } \
        } \
    } while (0)

    // preamble: A two tiles ahead, B one tile ahead
    LOADA(rA0, kbeg);
    LOADA(rA1, kbeg + 64);
    LOADB(kbeg);

    for (int it = 0; it < 16; it += 2) {
        // even step: consumes rA0 / rB (tile it)
        __syncthreads();
        STOREA(rA0);
        STOREB();
        __syncthreads();
        if (it + 1 < 16) LOADB(kbeg + (it + 1) * 64);   // B first: depth-2 A stays in flight
        if (it + 2 < 16) LOADA(rA0, kbeg + (it + 2) * 64);
        COMPUTE();
        // odd step: consumes rA1 / rB (tile it+1)
        __syncthreads();
        STOREA(rA1);
        STOREB();
        __syncthreads();
        if (it + 2 < 16) LOADB(kbeg + (it + 2) * 64);
        if (it + 3 < 16) LOADA(rA1, kbeg + (it + 3) * 64);
        COMPUTE();
    }

    // epilogue: C/D layout col=lane&15, row=quad*4+reg; fp16 private partial per K-split
    unsigned short* out = Cp16 + (size_t)ks * (NAG * NB);
    #pragma unroll
    for (int j = 0; j < 9; ++j) {
        int col = j * 16 + fm;
        #pragma unroll
        for (int r = 0; r < 4; ++r) {
            int row = row0 + wave * 16 + quad * 4 + r;
            out[(size_t)row * NB + col] = f2h(acc[j][r]);
        }
    }
#undef LOADA
#undef LOADB
#undef STOREA
#undef STOREB
#undef COMPUTE
}

// ---------------- Kernel 3: reduce fp16 partials, msg=sum/deg, actor MLP ----------------
// 16 agents/block -> 512 blocks (2/CU); float4 LDS inner loop.
__global__ __launch_bounds__(256) void k3_actor(
    const float* __restrict__ h_f32,          // [8192][128]
    const unsigned short* __restrict__ Cp16,  // [NSPLIT][8192][144] fp16
    const void* __restrict__ W2,              // [256][128]
    const void* __restrict__ b2,              // [128]
    const void* __restrict__ W3,              // [128][16]
    const void* __restrict__ b3,              // [16]
    const int* __restrict__ flag,
    void* __restrict__ out)                   // [8192][16]
{
    __shared__ float4 comb4[16][66];   // [agent][c-quad], c = 0..255
    __shared__ float hid[16][132];
    __shared__ float inv_lds[16];
    const int t = threadIdx.x;
    const int abase = blockIdx.x * 16;
    const bool isf = (*flag != 0);
    const size_t PS = (size_t)NAG * NB;

    if (t < 16) {
        float deg = 0.f;
        #pragma unroll
        for (int s = 0; s < NSPLIT; ++s)
            deg += h2f(Cp16[s * PS + (size_t)(abase + t) * NB + 128]);
        inv_lds[t] = 1.0f / fmaxf(deg, 1.0f);
    }
    __syncthreads();

    // stage comb: 16 agents x 64 c-quads; 1024 tasks over 256 threads
    #pragma unroll
    for (int jj = 0; jj < 4; ++jj) {
        int idx = jj * 256 + t;
        int a = idx >> 6, q = idx & 63;
        float4 v;
        if (q < 32) {   // h part
            v = *reinterpret_cast<const float4*>(h_f32 + (size_t)(abase + a) * 128 + q * 4);
        } else {        // msg part: sum NSPLIT fp16 partials, scale by 1/deg
            int f = (q - 32) * 4;
            float s0 = 0.f, s1 = 0.f, s2 = 0.f, s3 = 0.f;
            #pragma unroll
            for (int s = 0; s < NSPLIT; ++s) {
                ushort4 p = *reinterpret_cast<const ushort4*>(Cp16 + s * PS + (size_t)(abase + a) * NB + f);
                s0 += h2f(p.x); s1 += h2f(p.y); s2 += h2f(p.z); s3 += h2f(p.w);
            }
            float sc = inv_lds[a];
            v = make_float4(s0 * sc, s1 * sc, s2 * sc, s3 * sc);
        }
        comb4[a][q] = v;
    }
    __syncthreads();

    const int o = t & 127, half = t >> 7;   // 8 agents per half
    float acc[8];
    if (isf) {
        const float* Wp = (const float*)W2;
        float bias = ((const float*)b2)[o];
        #pragma unroll
        for (int i = 0; i < 8; ++i) acc[i] = bias;
        for (int cq = 0; cq < 64; ++cq) {
            float w0 = Wp[(cq * 4 + 0) * 128 + o];
            float w1 = Wp[(cq * 4 + 1) * 128 + o];
            float w2 = Wp[(cq * 4 + 2) * 128 + o];
            float w3 = Wp[(cq * 4 + 3) * 128 + o];
            #pragma unroll
            for (int i = 0; i < 8; ++i) {
                float4 v = comb4[half * 8 + i][cq];
                acc[i] = fmaf(v.x, w0, acc[i]);
                acc[i] = fmaf(v.y, w1, acc[i]);
                acc[i] = fmaf(v.z, w2, acc[i]);
                acc[i] = fmaf(v.w, w3, acc[i]);
            }
        }
    } else {
        const unsigned short* Wp = (const unsigned short*)W2;
        float bias = bf2f(((const unsigned short*)b2)[o]);
        #pragma unroll
        for (int i = 0; i < 8; ++i) acc[i] = bias;
        for (int cq = 0; cq < 64; ++cq) {
            float w0 = bf2f(Wp[(cq * 4 + 0) * 128 + o]);
            float w1 = bf2f(Wp[(cq * 4 + 1) * 128 + o]);
            float w2 = bf2f(Wp[(cq * 4 + 2) * 128 + o]);
            float w3 = bf2f(Wp[(cq * 4 + 3) * 128 + o]);
            #pragma unroll
            for (int i = 0; i < 8; ++i) {
                float4 v = comb4[half * 8 + i][cq];
                acc[i] = fmaf(v.x, w0, acc[i]);
                acc[i] = fmaf(v.y, w1, acc[i]);
                acc[i] = fmaf(v.z, w2, acc[i]);
                acc[i] = fmaf(v.w, w3, acc[i]);
            }
        }
    }
    #pragma unroll
    for (int i = 0; i < 8; ++i)
        hid[half * 8 + i][o] = tanhf(acc[i]);
    __syncthreads();

    const int q = t & 15, ar = t >> 4;   // 16 agents x 16 outputs = 256 threads
    float l;
    if (isf) {
        const float* Wp = (const float*)W3;
        l = ((const float*)b3)[q];
        #pragma unroll 4
        for (int oo = 0; oo < 128; ++oo)
            l = fmaf(hid[ar][oo], Wp[oo * 16 + q], l);
    } else {
        const unsigned short* Wp = (const unsigned short*)W3;
        l = bf2f(((const unsigned short*)b3)[q]);
        #pragma unroll 4
        for (int oo = 0; oo < 128; ++oo)
            l = fmaf(hid[ar][oo], bf2f(Wp[oo * 16 + q]), l);
    }
    size_t i0 = (size_t)(abase + ar) * 16 + q;
    if (isf) ((float*)out)[i0] = l;
    else     ((unsigned short*)out)[i0] = f2bf(l);
}

extern "C" void kernel_launch(void* const* d_in, const int* in_sizes, int n_in,
                              void* d_out, int out_size, void* d_ws, size_t ws_size,
                              hipStream_t stream) {
    const void* obs = d_in[0];
    const int*  adj = (const int*)d_in[1];
    const void* W1  = d_in[2];
    const void* b1  = d_in[3];
    const void* W2  = d_in[4];
    const void* b2  = d_in[5];
    const void* W3  = d_in[6];
    const void* b3  = d_in[7];

    char* ws = (char*)d_ws;
    unsigned short* hT   = (unsigned short*)(ws);               // 144*8192*2      =  2,359,296 B
    float*          h_f32= (float*)(ws + 2359296);              // 8192*128*4      =  4,194,304 B
    unsigned short* Cp16 = (unsigned short*)(ws + 6553600);     // 8*8192*144*2    = 18,874,368 B
    int*            flag = (int*)(ws + 25427968);               // 4 B   (total ~25.4 MB)

    hipLaunchKernelGGL(k0_init, dim3(1), dim3(64), 0, stream, flag, (const unsigned short*)W1);
    hipLaunchKernelGGL(k1_encode, dim3(256), dim3(256), 0, stream, obs, W1, b1, flag, h_f32, hT);
    hipLaunchKernelGGL(k2_msggemm, dim3(1024), dim3(256), 0, stream, adj, hT, Cp16);
    hipLaunchKernelGGL(k3_actor, dim3(512), dim3(256), 0, stream, h_f32, Cp16, W2, b2, W3, b3, flag, d_out);
}

// Round 8
// 467.000 us; speedup vs baseline: 1.1182x; 1.1182x over previous
//
#include <hip/hip_runtime.h>
#include <stdint.h>
#include <math.h>

#define NAG 8192
#define NB  144          // partial row stride: 128 feats + deg col(128) + pad to 9*16
#define BM  64           // M rows per block
#define NSPLIT 8         // K splits (fp16 private partials, no atomics)

typedef __attribute__((ext_vector_type(8))) short short8;
typedef __attribute__((ext_vector_type(4))) float floatx4;

__device__ __forceinline__ float bf2f(unsigned short u) {
    union { uint32_t i; float f; } v; v.i = ((uint32_t)u) << 16; return v.f;
}
__device__ __forceinline__ unsigned short f2bf(float f) {
    union { float f; uint32_t i; } v; v.f = f;
    uint32_t x = v.i;
    return (unsigned short)((x + 0x7FFFu + ((x >> 16) & 1u)) >> 16);  // RNE
}
__device__ __forceinline__ unsigned short f2h(float f) {
    union { _Float16 h; unsigned short u; } v; v.h = (_Float16)f; return v.u;
}
__device__ __forceinline__ float h2f(unsigned short u) {
    union { _Float16 h; unsigned short u; } v; v.u = u; return (float)v.h;
}
// async global->LDS DMA, 16 B/lane; lds dest must be wave-uniform base (lane*16 implicit)
__device__ __forceinline__ void gload_lds16(const void* g, void* lds) {
    __builtin_amdgcn_global_load_lds(
        (const __attribute__((address_space(1))) uint32_t*)g,
        (__attribute__((address_space(3))) uint32_t*)lds, 16, 0, 0);
}

// ---------------- Kernel 0: detect float storage dtype from W1 raw bits ----------------
__global__ __launch_bounds__(64) void k0_init(
    int* __restrict__ flag, const unsigned short* __restrict__ W1raw)
{
    int big = 0;
    #pragma unroll
    for (int j = 0; j < 8; ++j) {
        float v = bf2f(W1raw[threadIdx.x * 8 + j]);
        if (!(fabsf(v) <= 1e6f)) big = 1;   // catches huge and NaN (fp32 mantissa noise)
    }
    unsigned long long m = __ballot(big);
    if (threadIdx.x == 0) *flag = (m != 0ull) ? 1 : 0;
}

// ---------------- Kernel 1: h = tanh(obs@W1+b1); write h_f32 and hT_bf16 ----------------
__global__ __launch_bounds__(256) void k1_encode(
    const void* __restrict__ obs,   // [8192][64] fp32 or bf16
    const void* __restrict__ W1,    // [64][128]
    const void* __restrict__ b1,    // [128]
    const int* __restrict__ flag,
    float* __restrict__ h_f32,      // [8192][128]
    unsigned short* __restrict__ hT)// [144][8192] bf16 (row128=ones, 129..143=0)
{
    __shared__ float obs_lds[32][68];
    __shared__ unsigned short ht_lds[128][33];
    const int t = threadIdx.x;
    const int abase = blockIdx.x * 32;
    const bool isf = (*flag != 0);

    {   // stage obs tile 32x64
        int a = t >> 3, c0 = (t & 7) * 8;
        if (isf) {
            const float* p = (const float*)obs;
            #pragma unroll
            for (int j = 0; j < 8; ++j)
                obs_lds[a][c0 + j] = p[(size_t)(abase + a) * 64 + c0 + j];
        } else {
            const unsigned short* p = (const unsigned short*)obs;
            #pragma unroll
            for (int j = 0; j < 8; ++j)
                obs_lds[a][c0 + j] = bf2f(p[(size_t)(abase + a) * 64 + c0 + j]);
        }
    }
    __syncthreads();

    const int o = t & 127;
    const int half = t >> 7;          // wave-uniform
    float acc[16];
    if (isf) {
        const float* Wp = (const float*)W1;
        float bias = ((const float*)b1)[o];
        #pragma unroll
        for (int i = 0; i < 16; ++i) acc[i] = bias;
        for (int k0 = 0; k0 < 64; k0 += 8) {
            float w[8];
            #pragma unroll
            for (int j = 0; j < 8; ++j) w[j] = Wp[(k0 + j) * 128 + o];
            #pragma unroll
            for (int j = 0; j < 8; ++j)
                #pragma unroll
                for (int i = 0; i < 16; ++i)
                    acc[i] = fmaf(obs_lds[half * 16 + i][k0 + j], w[j], acc[i]);
        }
    } else {
        const unsigned short* Wp = (const unsigned short*)W1;
        float bias = bf2f(((const unsigned short*)b1)[o]);
        #pragma unroll
        for (int i = 0; i < 16; ++i) acc[i] = bias;
        for (int k0 = 0; k0 < 64; k0 += 8) {
            float w[8];
            #pragma unroll
            for (int j = 0; j < 8; ++j) w[j] = bf2f(Wp[(k0 + j) * 128 + o]);
            #pragma unroll
            for (int j = 0; j < 8; ++j)
                #pragma unroll
                for (int i = 0; i < 16; ++i)
                    acc[i] = fmaf(obs_lds[half * 16 + i][k0 + j], w[j], acc[i]);
        }
    }
    #pragma unroll
    for (int i = 0; i < 16; ++i) {
        float th = tanhf(acc[i]);
        int a = half * 16 + i;
        h_f32[(size_t)(abase + a) * 128 + o] = th;
        ht_lds[o][a] = f2bf(th);
    }
    __syncthreads();

    for (int p = 0; p < 18; ++p) {
        int n = p * 8 + (t >> 5);
        int a = t & 31;
        unsigned short v;
        if (n < 128)       v = ht_lds[n][a];
        else if (n == 128) v = 0x3F80;     // 1.0 bf16 -> deg column
        else               v = 0;
        hT[(size_t)n * NAG + abase + a] = v;
    }
}

// ---------------- Kernel 2: Cp16[ks] = adj[:, kslice] @ [h|1|0]  (bf16 MFMA) ----------------
// ZERO staging registers: global_load_lds (16B) DMAs A (raw int32) and B (bf16) to LDS.
// XOR-swizzled chunk layout (applied via source-address permutation at issue time, since
// the DMA forbids padding) -> conflict-light fragment reads. A converted int->bf16 at
// fragment-read (values {0,1} exact via (x|y<<16)*0x3F80). 9 uniform N-tiles per wave.
__global__ __launch_bounds__(256, 4) void k2_msggemm(
    const int* __restrict__ adj,              // [8192][8192] int32 {0,1}
    const unsigned short* __restrict__ hT,    // [144][8192] bf16
    unsigned short* __restrict__ Cp16)        // [NSPLIT][8192][144] fp16
{
    __shared__ __align__(16) int Alds[64 * 64];               // 16384 B, rows of 64 int32
    __shared__ __align__(16) unsigned short Blds[144 * 64];   // 18432 B, rows of 64 bf16
    const int t = threadIdx.x;
    const int mtile = blockIdx.x & 127;       // 128 M-tiles of 64 rows
    const int ks = blockIdx.x >> 7;           // 8 K-splits of 1024
    const int row0 = mtile * BM;
    const int kbeg = ks * 1024;

    const int wave = t >> 6, lane = t & 63;
    const int fm = lane & 15, quad = lane >> 4;

    floatx4 acc[9];
    #pragma unroll
    for (int i = 0; i < 9; ++i) acc[i] = (floatx4)0.f;

    // --- staging source pointers (swizzle via source permutation) ---
    // A: issue i (=wave*4+s) covers rows 4i..4i+3; lane -> row 4i+(l>>4), phys chunk l&15,
    //    source chunk c = (l&15) ^ (row&15). chunk = 4 ints = 16 B.
    const int ra0 = 16 * wave + (lane >> 4);          // row for s=0; s adds 4
    const int* a0 = adj + (size_t)(row0 + ra0 +  0) * NAG + kbeg + (((lane & 15) ^ ((ra0 +  0) & 15)) << 2);
    const int* a1 = adj + (size_t)(row0 + ra0 +  4) * NAG + kbeg + (((lane & 15) ^ ((ra0 +  4) & 15)) << 2);
    const int* a2 = adj + (size_t)(row0 + ra0 +  8) * NAG + kbeg + (((lane & 15) ^ ((ra0 +  8) & 15)) << 2);
    const int* a3 = adj + (size_t)(row0 + ra0 + 12) * NAG + kbeg + (((lane & 15) ^ ((ra0 + 12) & 15)) << 2);
    // B: issue j (=wave*4+s) covers rows 8j..8j+7; lane -> row 8j+(l>>3), phys chunk l&7,
    //    source chunk c = (l&7) ^ ((l>>3)&7). chunk = 8 shorts = 16 B.
    const int rb0 = 32 * wave + (lane >> 3);          // row for s=0; s adds 8
    const int bco = (((lane & 7) ^ ((lane >> 3) & 7)) << 3);
    const unsigned short* b0 = hT + (size_t)(rb0 +  0) * NAG + kbeg + bco;
    const unsigned short* b1 = hT + (size_t)(rb0 +  8) * NAG + kbeg + bco;
    const unsigned short* b2 = hT + (size_t)(rb0 + 16) * NAG + kbeg + bco;
    const unsigned short* b3 = hT + (size_t)(rb0 + 24) * NAG + kbeg + bco;
    // wave-uniform LDS destinations (1 KB per issue)
    int* Ad0 = &Alds[(wave * 4 + 0) * 256];
    int* Ad1 = &Alds[(wave * 4 + 1) * 256];
    int* Ad2 = &Alds[(wave * 4 + 2) * 256];
    int* Ad3 = &Alds[(wave * 4 + 3) * 256];
    unsigned short* Bd0 = &Blds[(wave * 4 + 0) * 512];
    unsigned short* Bd1 = &Blds[(wave * 4 + 1) * 512];
    unsigned short* Bd2 = &Blds[(wave * 4 + 2) * 512];
    unsigned short* Bd3 = &Blds[(wave * 4 + 3) * 512];

    // constant B rows 128..143 (swizzle-invariant: uniform within row), written once
    {
        int rr = 128 + (t >> 4);
        int off = (t & 15) * 4;
        uint32_t vv = (rr == 128) ? 0x3F803F80u : 0u;   // 1.0|1.0 bf16 for deg row
        *reinterpret_cast<uint2*>(&Blds[rr * 64 + off]) = make_uint2(vv, vv);
    }

    for (int it = 0; it < 16; ++it) {
        const int ko = it * 64;
        __syncthreads();                 // previous compute done before DMA overwrites LDS
        gload_lds16(a0 + ko, Ad0);       // A first: HBM latency starts earliest
        gload_lds16(a1 + ko, Ad1);
        gload_lds16(a2 + ko, Ad2);
        gload_lds16(a3 + ko, Ad3);
        gload_lds16(b0 + ko, Bd0);       // B is L2-hot (hT = 2.4 MB)
        gload_lds16(b1 + ko, Bd1);
        gload_lds16(b2 + ko, Bd2);
        gload_lds16(b3 + ko, Bd3);
        __syncthreads();                 // compiler drains vmcnt(0) before s_barrier -> tile resident
        #pragma unroll
        for (int kk = 0; kk < 64; kk += 32) {
            // A fragment: rows wave*16+fm, ints kk+quad*8..+7 (source chunks c0,c0+1)
            const int arow = (wave * 16 + fm) * 64;
            const int c0 = (kk >> 2) + 2 * quad;
            int4 v0 = *reinterpret_cast<const int4*>(&Alds[arow + (((c0 + 0) ^ fm) << 2)]);
            int4 v1 = *reinterpret_cast<const int4*>(&Alds[arow + (((c0 + 1) ^ fm) << 2)]);
            union { uint32_t u[4]; short8 s; } af;
            af.u[0] = ((uint32_t)v0.x | ((uint32_t)v0.y << 16)) * 0x3F80u;
            af.u[1] = ((uint32_t)v0.z | ((uint32_t)v0.w << 16)) * 0x3F80u;
            af.u[2] = ((uint32_t)v1.x | ((uint32_t)v1.y << 16)) * 0x3F80u;
            af.u[3] = ((uint32_t)v1.z | ((uint32_t)v1.w << 16)) * 0x3F80u;
            const int bc = (kk >> 3) + quad;          // source chunk 0..7
            #pragma unroll
            for (int j = 0; j < 9; ++j) {
                int rb = j * 16 + fm;
                short8 bf = *reinterpret_cast<const short8*>(&Blds[rb * 64 + ((bc ^ (fm & 7)) << 3)]);
                acc[j] = __builtin_amdgcn_mfma_f32_16x16x32_bf16(af.s, bf, acc[j], 0, 0, 0);
            }
        }
    }

    // epilogue: C/D layout col=lane&15, row=quad*4+reg; fp16 private partial per K-split
    unsigned short* out = Cp16 + (size_t)ks * (NAG * NB);
    #pragma unroll
    for (int j = 0; j < 9; ++j) {
        int col = j * 16 + fm;
        #pragma unroll
        for (int r = 0; r < 4; ++r) {
            int row = row0 + wave * 16 + quad * 4 + r;
            out[(size_t)row * NB + col] = f2h(acc[j][r]);
        }
    }
}

// ---------------- Kernel 3: reduce fp16 partials, msg=sum/deg, actor MLP ----------------
__global__ __launch_bounds__(256) void k3_actor(
    const float* __restrict__ h_f32,          // [8192][128]
    const unsigned short* __restrict__ Cp16,  // [NSPLIT][8192][144] fp16
    const void* __restrict__ W2,              // [256][128]
    const void* __restrict__ b2,              // [128]
    const void* __restrict__ W3,              // [128][16]
    const void* __restrict__ b3,              // [16]
    const int* __restrict__ flag,
    void* __restrict__ out)                   // [8192][16]
{
    __shared__ float4 comb4[16][66];   // [agent][c-quad], c = 0..255
    __shared__ float hid[16][132];
    __shared__ float inv_lds[16];
    const int t = threadIdx.x;
    const int abase = blockIdx.x * 16;
    const bool isf = (*flag != 0);
    const size_t PS = (size_t)NAG * NB;

    if (t < 16) {
        float deg = 0.f;
        #pragma unroll
        for (int s = 0; s < NSPLIT; ++s)
            deg += h2f(Cp16[s * PS + (size_t)(abase + t) * NB + 128]);
        inv_lds[t] = 1.0f / fmaxf(deg, 1.0f);
    }
    __syncthreads();

    #pragma unroll
    for (int jj = 0; jj < 4; ++jj) {
        int idx = jj * 256 + t;
        int a = idx >> 6, q = idx & 63;
        float4 v;
        if (q < 32) {   // h part
            v = *reinterpret_cast<const float4*>(h_f32 + (size_t)(abase + a) * 128 + q * 4);
        } else {        // msg part: sum NSPLIT fp16 partials, scale by 1/deg
            int f = (q - 32) * 4;
            float s0 = 0.f, s1 = 0.f, s2 = 0.f, s3 = 0.f;
            #pragma unroll
            for (int s = 0; s < NSPLIT; ++s) {
                ushort4 p = *reinterpret_cast<const ushort4*>(Cp16 + s * PS + (size_t)(abase + a) * NB + f);
                s0 += h2f(p.x); s1 += h2f(p.y); s2 += h2f(p.z); s3 += h2f(p.w);
            }
            float sc = inv_lds[a];
            v = make_float4(s0 * sc, s1 * sc, s2 * sc, s3 * sc);
        }
        comb4[a][q] = v;
    }
    __syncthreads();

    const int o = t & 127, half = t >> 7;   // 8 agents per half
    float acc[8];
    if (isf) {
        const float* Wp = (const float*)W2;
        float bias = ((const float*)b2)[o];
        #pragma unroll
        for (int i = 0; i < 8; ++i) acc[i] = bias;
        for (int cq = 0; cq < 64; ++cq) {
            float w0 = Wp[(cq * 4 + 0) * 128 + o];
            float w1 = Wp[(cq * 4 + 1) * 128 + o];
            float w2 = Wp[(cq * 4 + 2) * 128 + o];
            float w3 = Wp[(cq * 4 + 3) * 128 + o];
            #pragma unroll
            for (int i = 0; i < 8; ++i) {
                float4 v = comb4[half * 8 + i][cq];
                acc[i] = fmaf(v.x, w0, acc[i]);
                acc[i] = fmaf(v.y, w1, acc[i]);
                acc[i] = fmaf(v.z, w2, acc[i]);
                acc[i] = fmaf(v.w, w3, acc[i]);
            }
        }
    } else {
        const unsigned short* Wp = (const unsigned short*)W2;
        float bias = bf2f(((const unsigned short*)b2)[o]);
        #pragma unroll
        for (int i = 0; i < 8; ++i) acc[i] = bias;
        for (int cq = 0; cq < 64; ++cq) {
            float w0 = bf2f(Wp[(cq * 4 + 0) * 128 + o]);
            float w1 = bf2f(Wp[(cq * 4 + 1) * 128 + o]);
            float w2 = bf2f(Wp[(cq * 4 + 2) * 128 + o]);
            float w3 = bf2f(Wp[(cq * 4 + 3) * 128 + o]);
            #pragma unroll
            for (int i = 0; i < 8; ++i) {
                float4 v = comb4[half * 8 + i][cq];
                acc[i] = fmaf(v.x, w0, acc[i]);
                acc[i] = fmaf(v.y, w1, acc[i]);
                acc[i] = fmaf(v.z, w2, acc[i]);
                acc[i] = fmaf(v.w, w3, acc[i]);
            }
        }
    }
    #pragma unroll
    for (int i = 0; i < 8; ++i)
        hid[half * 8 + i][o] = tanhf(acc[i]);
    __syncthreads();

    const int q = t & 15, ar = t >> 4;
    float l;
    if (isf) {
        const float* Wp = (const float*)W3;
        l = ((const float*)b3)[q];
        #pragma unroll 4
        for (int oo = 0; oo < 128; ++oo)
            l = fmaf(hid[ar][oo], Wp[oo * 16 + q], l);
    } else {
        const unsigned short* Wp = (const unsigned short*)W3;
        l = bf2f(((const unsigned short*)b3)[q]);
        #pragma unroll 4
        for (int oo = 0; oo < 128; ++oo)
            l = fmaf(hid[ar][oo], bf2f(Wp[oo * 16 + q]), l);
    }
    size_t i0 = (size_t)(abase + ar) * 16 + q;
    if (isf) ((float*)out)[i0] = l;
    else     ((unsigned short*)out)[i0] = f2bf(l);
}

extern "C" void kernel_launch(void* const* d_in, const int* in_sizes, int n_in,
                              void* d_out, int out_size, void* d_ws, size_t ws_size,
                              hipStream_t stream) {
    const void* obs = d_in[0];
    const int*  adj = (const int*)d_in[1];
    const void* W1  = d_in[2];
    const void* b1  = d_in[3];
    const void* W2  = d_in[4];
    const void* b2  = d_in[5];
    const void* W3  = d_in[6];
    const void* b3  = d_in[7];

    char* ws = (char*)d_ws;
    unsigned short* hT   = (unsigned short*)(ws);               // 144*8192*2   =  2,359,296 B
    float*          h_f32= (float*)(ws + 2359296);              // 8192*128*4   =  4,194,304 B
    unsigned short* Cp16 = (unsigned short*)(ws + 6553600);     // 8*8192*144*2 = 18,874,368 B
    int*            flag = (int*)(ws + 25427968);               // 4 B  (total ~25.4 MB)

    hipLaunchKernelGGL(k0_init, dim3(1), dim3(64), 0, stream, flag, (const unsigned short*)W1);
    hipLaunchKernelGGL(k1_encode, dim3(256), dim3(256), 0, stream, obs, W1, b1, flag, h_f32, hT);
    hipLaunchKernelGGL(k2_msggemm, dim3(1024), dim3(256), 0, stream, adj, hT, Cp16);
    hipLaunchKernelGGL(k3_actor, dim3(512), dim3(256), 0, stream, h_f32, Cp16, W2, b2, W3, b3, flag, d_out);
}